// Round 7
// baseline (423.640 us; speedup 1.0000x reference)
//
#include <hip/hip_runtime.h>
#include <stdint.h>

#ifndef FLT_MAX
#define FLT_MAX 3.402823466e+38f
#endif

typedef unsigned short ushort_t;
typedef unsigned long long u64;

static constexpr int NTOK = 16384;   // B*S
static constexpr int DD   = 512;
static constexpr int KK   = 1024;

static constexpr float DECAYF = 0.99f;
static constexpr float OMDEC  = 0.01f;
static constexpr float EPSF   = 1e-5f;
static constexpr float EPSM   = 0.05f;   // rescore margin (split-bf16 error ~1e-4, huge safety)

using bf16x8 = __attribute__((ext_vector_type(8))) __bf16;
using f32x4v = __attribute__((ext_vector_type(4))) float;

// ---- helpers ----
__device__ __forceinline__ unsigned f2bf(float f) {           // RNE f32->bf16 bits
    unsigned u = __float_as_uint(f);
    return (u + 0x7fffu + ((u >> 16) & 1u)) >> 16;
}
__device__ __forceinline__ float bf2f(unsigned h) { return __uint_as_float(h << 16); }
__device__ __forceinline__ unsigned encf(float f) {           // sortable float
    unsigned u = __float_as_uint(f);
    return (u & 0x80000000u) ? ~u : (u | 0x80000000u);
}
__device__ __forceinline__ float decf(unsigned e) {
    unsigned u = (e & 0x80000000u) ? (e ^ 0x80000000u) : ~e;
    return __uint_as_float(u);
}
__device__ __forceinline__ void top2_ins(u64& k1, u64& k2, u64 k) {
    if (k < k1) { k2 = k1; k1 = k; } else if (k < k2) { k2 = k; }
}
__device__ __forceinline__ void top2_mrg(u64& k1, u64& k2, u64 o1, u64 o2) {
    u64 lo = k1 < o1 ? k1 : o1;
    u64 hi = k1 < o1 ? o1 : k1;
    u64 m2 = k2 < o2 ? k2 : o2;
    u64 nk2 = hi < m2 ? hi : m2;
    k1 = lo; k2 = nk2;
}

// ---------------- fused prep: z hi/lo split + codebook split/cnorm + zero accs ----------------
// blocks [0,4096): z-split (blocks [0,512) also zero dwacc)
// blocks [4096,5120): one codebook row each (split + 0.5*||c||^2)
// block 5120: zero nmask + fix_cnt
__global__ void k_prep(const float* __restrict__ z, const float* __restrict__ cw,
                       ushort_t* __restrict__ zh, ushort_t* __restrict__ zl,
                       ushort_t* __restrict__ ch, ushort_t* __restrict__ cl,
                       float* __restrict__ cnorm, float* __restrict__ nmask,
                       int* __restrict__ fix_cnt, float* __restrict__ dwacc)
{
    const int bid = blockIdx.x, tid = threadIdx.x;
    __shared__ float rs[256];
    if (bid < 4096) {
        size_t i = ((size_t)bid * 256 + tid) * 8;
        float4 v0 = *reinterpret_cast<const float4*>(z + i);
        float4 v1 = *reinterpret_cast<const float4*>(z + i + 4);
        float f[8] = {v0.x, v0.y, v0.z, v0.w, v1.x, v1.y, v1.z, v1.w};
        union { ushort_t u[8]; uint4 v; } H, L;
#pragma unroll
        for (int e = 0; e < 8; ++e) {
            unsigned h = f2bf(f[e]);
            H.u[e] = (ushort_t)h;
            L.u[e] = (ushort_t)f2bf(f[e] - bf2f(h));
        }
        *reinterpret_cast<uint4*>(zh + i) = H.v;
        *reinterpret_cast<uint4*>(zl + i) = L.v;
        if (bid < 512) {
            const float4 zf4 = make_float4(0.f, 0.f, 0.f, 0.f);
            *reinterpret_cast<float4*>(dwacc + ((size_t)bid * 256 + tid) * 4) = zf4;
        }
    } else if (bid < 5120) {
        const int k = bid - 4096;
        const size_t o = (size_t)k * DD + tid * 2;
        float2 v = *reinterpret_cast<const float2*>(cw + o);
        unsigned h0 = f2bf(v.x), h1 = f2bf(v.y);
        unsigned l0 = f2bf(v.x - bf2f(h0)), l1 = f2bf(v.y - bf2f(h1));
        *reinterpret_cast<unsigned*>(ch + o) = h0 | (h1 << 16);
        *reinterpret_cast<unsigned*>(cl + o) = l0 | (l1 << 16);
        rs[tid] = v.x * v.x + v.y * v.y;
        __syncthreads();
        for (int s = 128; s > 0; s >>= 1) { if (tid < s) rs[tid] += rs[tid + s]; __syncthreads(); }
        if (tid == 0) cnorm[k] = 0.5f * rs[0];
    } else {
        for (int i = tid; i < KK; i += 256) nmask[i] = 0.f;
        if (tid == 0) fix_cnt[0] = 0;
    }
}

// ---------------- MFMA score kernel: 2-phase double-buffered staging ----------------
// grid (128 token-tiles, 8 code-tiles), 256 thr = 4 waves (2x2 over 128x128 tile)
__global__ __launch_bounds__(256, 2) void k_scores(
    const ushort_t* __restrict__ zh, const ushort_t* __restrict__ zl,
    const ushort_t* __restrict__ ch, const ushort_t* __restrict__ cl,
    const float* __restrict__ cnorm, u64* __restrict__ top2)
{
    __shared__ ushort_t lds[2 * 4 * 128 * 32];    // 2 buffers x (zh,zl,ch,cl tiles) = 2 x 32KB
    const int tid = threadIdx.x;
    const int lane = tid & 63;
    const int wid = tid >> 6;
    const int wm = wid >> 1, wn = wid & 1;
    const int t0 = blockIdx.x * 128;
    const int c0 = blockIdx.y * 128;

    // staging: chunk q = issue*256+tid (16B each); row=q>>2, phys chunk=q&3
    // swizzle: source col8 = pch ^ ((row>>1)&3)  (involution; reads use same XOR)
    const int srow = tid >> 2;
    const int scol = ((tid & 3) ^ ((srow >> 1) & 3)) * 8;
    const size_t zo0 = (size_t)(t0 + srow) * DD + scol;
    const size_t zo1 = zo0 + (size_t)64 * DD;
    const size_t co0 = (size_t)(c0 + srow) * DD + scol;
    const size_t co1 = co0 + (size_t)64 * DD;

    const int l15 = lane & 15, kc = lane >> 4;
    int a_addr[4], b_addr[4];
#pragma unroll
    for (int i = 0; i < 4; ++i) {
        int ar = wm * 64 + i * 16 + l15;
        a_addr[i] = ar * 64 + ((kc ^ ((ar >> 1) & 3)) << 4);
        int br = wn * 64 + i * 16 + l15;
        b_addr[i] = br * 64 + ((kc ^ ((br >> 1) & 3)) << 4);
    }

    f32x4v acc[4][4];
    const f32x4v zf = {0.f, 0.f, 0.f, 0.f};
#pragma unroll
    for (int i = 0; i < 4; ++i)
#pragma unroll
        for (int j = 0; j < 4; ++j) acc[i][j] = zf;

    const char* ldsb = (const char*)lds;
    const int wbase = wid * 64;

    // STAGE(ptr, rowoff, issue_slot, dbyte_off_in_D, buf): lds elem offset = buf*16384 + (issue*256+wbase)*8
#define STAGE(PTR, OFF, ISSUE, D0, BUF)                                               \
    __builtin_amdgcn_global_load_lds(                                                 \
        (const __attribute__((address_space(1))) unsigned int*)((PTR) + (OFF) + (D0)),   \
        (__attribute__((address_space(3))) unsigned int*)(lds + (BUF) * 16384 + (((ISSUE) * 256 + wbase) * 8)), \
        16, 0, 0);
#define STAGE8(D0, BUF)                       \
    STAGE(zh, zo0, 0, D0, BUF) STAGE(zh, zo1, 1, D0, BUF) \
    STAGE(zl, zo0, 2, D0, BUF) STAGE(zl, zo1, 3, D0, BUF) \
    STAGE(ch, co0, 4, D0, BUF) STAGE(ch, co1, 5, D0, BUF) \
    STAGE(cl, co0, 6, D0, BUF) STAGE(cl, co1, 7, D0, BUF)

    // prologue: stage dk=0 into buffer 0, drain, barrier
    STAGE8(0, 0)
    __syncthreads();

    int cur = 0;
    for (int dk = 0; dk < 16; ++dk) {
        // issue next tile's loads into the other buffer FIRST (latency hides under MFMA)
        const int d0n = ((dk + 1) & 15) * 32;
        if (cur) { STAGE8(d0n, 0) } else { STAGE8(d0n, 1) }

        const char* base = ldsb + cur * 32768;
        bf16x8 ah[4], al[4], bh[4], bl[4];
#pragma unroll
        for (int i = 0; i < 4; ++i) {
            ah[i] = *(const bf16x8*)(base + a_addr[i]);
            al[i] = *(const bf16x8*)(base + 8192  + a_addr[i]);
            bh[i] = *(const bf16x8*)(base + 16384 + b_addr[i]);
            bl[i] = *(const bf16x8*)(base + 24576 + b_addr[i]);
        }
#pragma unroll
        for (int i = 0; i < 4; ++i)
#pragma unroll
            for (int j = 0; j < 4; ++j) {
                acc[i][j] = __builtin_amdgcn_mfma_f32_16x16x32_bf16(ah[i], bh[j], acc[i][j], 0, 0, 0);
                acc[i][j] = __builtin_amdgcn_mfma_f32_16x16x32_bf16(ah[i], bl[j], acc[i][j], 0, 0, 0);
                acc[i][j] = __builtin_amdgcn_mfma_f32_16x16x32_bf16(al[i], bh[j], acc[i][j], 0, 0, 0);
            }
        __syncthreads();    // single drain+barrier per K-step (vmcnt(0) for next tile, flip)
        cur ^= 1;
    }
#undef STAGE8
#undef STAGE

    // epilogue: s = 0.5||c||^2 - z.c ; per-row top-2 over this wave's 64 codes
    float cn[4];
#pragma unroll
    for (int j = 0; j < 4; ++j) cn[j] = cnorm[c0 + wn * 64 + j * 16 + l15];

    const int g = lane >> 4;
    const int part = blockIdx.y * 2 + wn;    // 16 partitions of 64 codes
#pragma unroll
    for (int i = 0; i < 4; ++i) {
#pragma unroll
        for (int r = 0; r < 4; ++r) {
            u64 k1 = ~0ULL, k2 = ~0ULL;
#pragma unroll
            for (int j = 0; j < 4; ++j) {
                float s = cn[j] - acc[i][j][r];
                u64 key = ((u64)encf(s) << 32) | (unsigned)(c0 + wn * 64 + j * 16 + l15);
                top2_ins(k1, k2, key);
            }
#pragma unroll
            for (int m = 1; m <= 8; m <<= 1) {
                u64 o1 = __shfl_xor(k1, m, 64);
                u64 o2 = __shfl_xor(k2, m, 64);
                top2_mrg(k1, k2, o1, o2);
            }
            if (l15 == 0) {
                int t = t0 + wm * 64 + i * 16 + g * 4 + r;
                top2[(size_t)(part * 2 + 0) * NTOK + t] = k1;
                top2[(size_t)(part * 2 + 1) * NTOK + t] = k2;
            }
        }
    }
}

// ---------------- merge 16 partition top-2s -> provisional argmin + fix flags ----------------
__global__ void k_merge(const u64* __restrict__ top2, int* __restrict__ idx_ws,
                        float* __restrict__ out_idx, int* __restrict__ fix_list,
                        int* __restrict__ fix_cnt, int* __restrict__ flag,
                        u64* __restrict__ packed2) {
    const int t = blockIdx.x * 256 + threadIdx.x;
    u64 k1 = ~0ULL, k2 = ~0ULL;
#pragma unroll
    for (int q = 0; q < 32; ++q) top2_ins(k1, k2, top2[(size_t)q * NTOK + t]);
    const int idx1 = (int)(k1 & 0xffffffffu);
    idx_ws[t] = idx1;
    out_idx[t] = (float)idx1;
    packed2[t] = ~0ULL;
    float v1 = decf((unsigned)(k1 >> 32));
    float v2 = decf((unsigned)(k2 >> 32));
    int f = (v2 - v1 < EPSM) ? 1 : 0;
    flag[t] = f;
    if (f) {
        int p = atomicAdd(fix_cnt, 1);
        fix_list[p] = t;
    }
}

// ---------------- exact f32 rescore: parallel over (token x 256-code chunk) ----------------
// grid-stride over nfix*4 work items; 16 lanes per code, 4 codes/wave in flight
__global__ void k_fixup(const float* __restrict__ z, const float* __restrict__ cw,
                        const float* __restrict__ cnorm, const int* __restrict__ fix_list,
                        const int* __restrict__ fix_cnt, u64* __restrict__ packed2)
{
    const int nwork = fix_cnt[0] * 4;
    const int tid = threadIdx.x, lane = tid & 63, wid = tid >> 6;
    const int l16 = lane & 15;
    const int sub = lane >> 4;       // 0..3: which of 4 parallel codes
    __shared__ float zrow[DD];
    __shared__ u64 best[4];
    for (int w = blockIdx.x; w < nwork; w += gridDim.x) {
        const int t = fix_list[w >> 2];
        const int cbase = (w & 3) * 256;
        if (tid < 128) {
            float4 v = *reinterpret_cast<const float4*>(z + (size_t)t * DD + tid * 4);
            *reinterpret_cast<float4*>(zrow + tid * 4) = v;
        }
        __syncthreads();
        u64 bk = ~0ULL;
        for (int it = 0; it < 16; ++it) {
            const int c = cbase + wid * 64 + it * 4 + sub;
            const float* cr = cw + (size_t)c * DD;
            float p = 0.f;
#pragma unroll
            for (int u = 0; u < 32; ++u) p = fmaf(zrow[l16 + u * 16], cr[l16 + u * 16], p);
#pragma unroll
            for (int m = 8; m > 0; m >>= 1) p += __shfl_xor(p, m, 16);
            if (l16 == 0) {
                u64 key = ((u64)encf(cnorm[c] - p) << 32) | (unsigned)c;
                if (key < bk) bk = key;
            }
        }
#pragma unroll
        for (int m = 16; m < 64; m <<= 1) {
            u64 o = __shfl_xor(bk, m, 64);
            if (o < bk) bk = o;
        }
        if (lane == 0) best[wid] = bk;
        __syncthreads();
        if (tid == 0) {
            u64 b = best[0];
            if (best[1] < b) b = best[1];
            if (best[2] < b) b = best[2];
            if (best[3] < b) b = best[3];
            atomicMin(&packed2[t], b);
        }
        __syncthreads();
    }
}

// ---------------- gather hidden + loss partials + direct-atomic dw/nmask ----------------
__global__ void k_post(const float* __restrict__ z, const float* __restrict__ mask,
                       const float* __restrict__ cw, int* __restrict__ idx_ws,
                       const int* __restrict__ flag, const u64* __restrict__ packed2,
                       float* __restrict__ out_hidden, float* __restrict__ out_idx,
                       float* __restrict__ partials, float* __restrict__ dwacc,
                       float* __restrict__ nmask)
{
    const int tid = threadIdx.x, lane = tid & 63, wid = tid >> 6;
    const int t = blockIdx.x * 4 + wid;
    int idx = idx_ws[t];
    if (flag[t]) {
        idx = (int)(packed2[t] & 0xffffffffu);
        if (lane == 0) { idx_ws[t] = idx; out_idx[t] = (float)idx; }
    }
    const float m = mask[t];
    const float* zr = z + (size_t)t * DD;
    const float* cr = cw + (size_t)idx * DD;
    float4 z0 = *reinterpret_cast<const float4*>(zr + lane * 4);
    float4 z1 = *reinterpret_cast<const float4*>(zr + 256 + lane * 4);
    float4 q0 = *reinterpret_cast<const float4*>(cr + lane * 4);
    float4 q1 = *reinterpret_cast<const float4*>(cr + 256 + lane * 4);
    float* hr = out_hidden + (size_t)t * DD;
    *reinterpret_cast<float4*>(hr + lane * 4) = q0;
    *reinterpret_cast<float4*>(hr + 256 + lane * 4) = q1;
    // segment-sum contribution: dw[idx] += m*z (coalesced distinct-address atomics)
    {
        float* db = dwacc + (size_t)idx * DD;
        atomicAdd(db + lane * 4 + 0, m * z0.x);
        atomicAdd(db + lane * 4 + 1, m * z0.y);
        atomicAdd(db + lane * 4 + 2, m * z0.z);
        atomicAdd(db + lane * 4 + 3, m * z0.w);
        atomicAdd(db + 256 + lane * 4 + 0, m * z1.x);
        atomicAdd(db + 256 + lane * 4 + 1, m * z1.y);
        atomicAdd(db + 256 + lane * 4 + 2, m * z1.z);
        atomicAdd(db + 256 + lane * 4 + 3, m * z1.w);
        if (lane == 0) atomicAdd(&nmask[idx], m);
    }
    float d2 = 0.f;
    float dx;
    dx = z0.x - q0.x; d2 = fmaf(dx, dx, d2);
    dx = z0.y - q0.y; d2 = fmaf(dx, dx, d2);
    dx = z0.z - q0.z; d2 = fmaf(dx, dx, d2);
    dx = z0.w - q0.w; d2 = fmaf(dx, dx, d2);
    dx = z1.x - q1.x; d2 = fmaf(dx, dx, d2);
    dx = z1.y - q1.y; d2 = fmaf(dx, dx, d2);
    dx = z1.z - q1.z; d2 = fmaf(dx, dx, d2);
    dx = z1.w - q1.w; d2 = fmaf(dx, dx, d2);
#pragma unroll
    for (int off = 32; off > 0; off >>= 1) d2 += __shfl_down(d2, off, 64);
    __shared__ float ls[4], ms[4];
    if (lane == 0) { ls[wid] = m * d2 * (1.f / DD); ms[wid] = m; }
    __syncthreads();
    if (tid == 0) {
        partials[blockIdx.x]        = ls[0] + ls[1] + ls[2] + ls[3];
        partials[4096 + blockIdx.x] = ms[0] + ms[1] + ms[2] + ms[3];
    }
}

// ---------------- fused tail: new_weight EMA + loss/new_count scalars ----------------
// 512 blocks: all do a 1024-float nw chunk; block 0 additionally does scalars
__global__ void k_tail(const float* __restrict__ ema_w, const float* __restrict__ dwacc,
                       const float* __restrict__ ema_count, const float* __restrict__ nmask,
                       const float* __restrict__ partials, float* __restrict__ out_nw,
                       float* __restrict__ out_count, float* __restrict__ out_loss)
{
    const int tid = threadIdx.x;
    const size_t i = ((size_t)blockIdx.x * 256 + tid) * 4;
    float4 e = *reinterpret_cast<const float4*>(ema_w + i);
    float4 d = *reinterpret_cast<const float4*>(dwacc + i);
    float4 r;
    r.x = DECAYF * e.x + OMDEC * d.x;
    r.y = DECAYF * e.y + OMDEC * d.y;
    r.z = DECAYF * e.z + OMDEC * d.z;
    r.w = DECAYF * e.w + OMDEC * d.w;
    *reinterpret_cast<float4*>(out_nw + i) = r;

    if (blockIdx.x == 0) {
        __shared__ float rl[256], rm[256], re[256];
        float ls = 0.f, ms = 0.f, es = 0.f;
        for (int j = tid; j < 4096; j += 256) { ls += partials[j]; ms += partials[4096 + j]; }
        for (int j = tid; j < KK; j += 256) es += ema_count[j];
        rl[tid] = ls; rm[tid] = ms; re[tid] = es;
        __syncthreads();
        for (int s = 128; s > 0; s >>= 1) {
            if (tid < s) { rl[tid] += rl[tid + s]; rm[tid] += rm[tid + s]; re[tid] += re[tid + s]; }
            __syncthreads();
        }
        const float masksum = rm[0];
        const float total = DECAYF * re[0] + OMDEC * masksum;
        const float scale = total / (total + KK * EPSF);
        for (int j = tid; j < KK; j += 256) {
            float raw = DECAYF * ema_count[j] + OMDEC * nmask[j];
            out_count[j] = (raw + EPSF) * scale;
        }
        if (tid == 0) out_loss[0] = 2.5f * rl[0] / masksum;   // LOSS_SCALE*COMMIT_COEF = 2.5
    }
}

extern "C" void kernel_launch(void* const* d_in, const int* in_sizes, int n_in,
                              void* d_out, int out_size, void* d_ws, size_t ws_size,
                              hipStream_t stream)
{
    const float* z         = (const float*)d_in[0];
    const float* mask      = (const float*)d_in[1];
    const float* cw        = (const float*)d_in[2];
    const float* ema_count = (const float*)d_in[3];
    const float* ema_w     = (const float*)d_in[4];

    float* out        = (float*)d_out;
    float* out_hidden = out;                               // [N, D]
    float* out_idx    = out + (size_t)NTOK * DD;           // [N]
    float* out_loss   = out_idx + NTOK;                    // [1]
    float* out_count  = out_loss + 1;                      // [K]
    float* out_nw     = out_count + KK;                    // [K, D]

    // workspace layout (~42 MB)
    ushort_t* zh   = (ushort_t*)d_ws;                      // 16 MB
    ushort_t* zl   = zh + (size_t)NTOK * DD;               // 16 MB
    ushort_t* ch   = zl + (size_t)NTOK * DD;               // 1 MB
    ushort_t* cl   = ch + (size_t)KK * DD;                 // 1 MB
    float* cnorm   = (float*)(cl + (size_t)KK * DD);       // 4 KB
    u64* top2      = (u64*)(cnorm + KK);                   // 32*N u64 = 4 MB
    u64* packed2   = top2 + (size_t)32 * NTOK;             // N u64 = 128 KB
    float* partials = (float*)(packed2 + NTOK);            // 8192 f32
    float* nmask   = partials + 8192;                      // 1024
    int* fix_list  = (int*)(nmask + KK);                   // N
    int* fix_cnt   = fix_list + NTOK;                      // 1 (+pad)
    int* flag      = fix_cnt + 16;                         // N
    int* idx_ws    = flag + NTOK;                          // N
    float* dwacc   = (float*)(idx_ws + NTOK);              // K*D f32 = 2 MB

    k_prep   <<<dim3(5121),     dim3(256),  0, stream>>>(z, cw, zh, zl, ch, cl, cnorm,
                                                         nmask, fix_cnt, dwacc);
    k_scores <<<dim3(128, 8),   dim3(256),  0, stream>>>(zh, zl, ch, cl, cnorm, top2);
    k_merge  <<<dim3(64),       dim3(256),  0, stream>>>(top2, idx_ws, out_idx, fix_list,
                                                         fix_cnt, flag, packed2);
    k_fixup  <<<dim3(2048),     dim3(256),  0, stream>>>(z, cw, cnorm, fix_list, fix_cnt, packed2);
    k_post   <<<dim3(4096),     dim3(256),  0, stream>>>(z, mask, cw, idx_ws, flag, packed2,
                                                         out_hidden, out_idx, partials, dwacc, nmask);
    k_tail   <<<dim3(512),      dim3(256),  0, stream>>>(ema_w, dwacc, ema_count, nmask,
                                                         partials, out_nw, out_count, out_loss);
}

// Round 8
// 283.369 us; speedup vs baseline: 1.4950x; 1.4950x over previous
//
#include <hip/hip_runtime.h>
#include <stdint.h>

#ifndef FLT_MAX
#define FLT_MAX 3.402823466e+38f
#endif

typedef unsigned short ushort_t;
typedef unsigned long long u64;

static constexpr int NTOK = 16384;   // B*S
static constexpr int DD   = 512;
static constexpr int KK   = 1024;

static constexpr float DECAYF = 0.99f;
static constexpr float OMDEC  = 0.01f;
static constexpr float EPSF   = 1e-5f;
static constexpr float EPSM   = 0.05f;   // rescore margin (split-bf16 error ~1e-4, huge safety)

using bf16x8 = __attribute__((ext_vector_type(8))) __bf16;
using f32x4v = __attribute__((ext_vector_type(4))) float;

// ---- helpers ----
__device__ __forceinline__ unsigned f2bf(float f) {           // RNE f32->bf16 bits
    unsigned u = __float_as_uint(f);
    return (u + 0x7fffu + ((u >> 16) & 1u)) >> 16;
}
__device__ __forceinline__ float bf2f(unsigned h) { return __uint_as_float(h << 16); }
__device__ __forceinline__ unsigned encf(float f) {           // sortable float
    unsigned u = __float_as_uint(f);
    return (u & 0x80000000u) ? ~u : (u | 0x80000000u);
}
__device__ __forceinline__ float decf(unsigned e) {
    unsigned u = (e & 0x80000000u) ? (e ^ 0x80000000u) : ~e;
    return __uint_as_float(u);
}
__device__ __forceinline__ void top2_ins(u64& k1, u64& k2, u64 k) {
    if (k < k1) { k2 = k1; k1 = k; } else if (k < k2) { k2 = k; }
}
__device__ __forceinline__ void top2_mrg(u64& k1, u64& k2, u64 o1, u64 o2) {
    u64 lo = k1 < o1 ? k1 : o1;
    u64 hi = k1 < o1 ? o1 : k1;
    u64 m2 = k2 < o2 ? k2 : o2;
    u64 nk2 = hi < m2 ? hi : m2;
    k1 = lo; k2 = nk2;
}

// ---------------- fused prep: z hi/lo split + codebook split/cnorm + zero accs ----------------
// blocks [0,4096): z-split (blocks [0,512) also zero dwacc)
// blocks [4096,5120): one codebook row each (split + 0.5*||c||^2)
// block 5120: zero nmask + cnt + fix_cnt
__global__ void k_prep(const float* __restrict__ z, const float* __restrict__ cw,
                       ushort_t* __restrict__ zh, ushort_t* __restrict__ zl,
                       ushort_t* __restrict__ ch, ushort_t* __restrict__ cl,
                       float* __restrict__ cnorm, float* __restrict__ nmask,
                       int* __restrict__ cnt, int* __restrict__ fix_cnt,
                       float* __restrict__ dwacc)
{
    const int bid = blockIdx.x, tid = threadIdx.x;
    __shared__ float rs[256];
    if (bid < 4096) {
        size_t i = ((size_t)bid * 256 + tid) * 8;
        float4 v0 = *reinterpret_cast<const float4*>(z + i);
        float4 v1 = *reinterpret_cast<const float4*>(z + i + 4);
        float f[8] = {v0.x, v0.y, v0.z, v0.w, v1.x, v1.y, v1.z, v1.w};
        union { ushort_t u[8]; uint4 v; } H, L;
#pragma unroll
        for (int e = 0; e < 8; ++e) {
            unsigned h = f2bf(f[e]);
            H.u[e] = (ushort_t)h;
            L.u[e] = (ushort_t)f2bf(f[e] - bf2f(h));
        }
        *reinterpret_cast<uint4*>(zh + i) = H.v;
        *reinterpret_cast<uint4*>(zl + i) = L.v;
        if (bid < 512) {
            const float4 zf4 = make_float4(0.f, 0.f, 0.f, 0.f);
            *reinterpret_cast<float4*>(dwacc + ((size_t)bid * 256 + tid) * 4) = zf4;
        }
    } else if (bid < 5120) {
        const int k = bid - 4096;
        const size_t o = (size_t)k * DD + tid * 2;
        float2 v = *reinterpret_cast<const float2*>(cw + o);
        unsigned h0 = f2bf(v.x), h1 = f2bf(v.y);
        unsigned l0 = f2bf(v.x - bf2f(h0)), l1 = f2bf(v.y - bf2f(h1));
        *reinterpret_cast<unsigned*>(ch + o) = h0 | (h1 << 16);
        *reinterpret_cast<unsigned*>(cl + o) = l0 | (l1 << 16);
        rs[tid] = v.x * v.x + v.y * v.y;
        __syncthreads();
        for (int s = 128; s > 0; s >>= 1) { if (tid < s) rs[tid] += rs[tid + s]; __syncthreads(); }
        if (tid == 0) cnorm[k] = 0.5f * rs[0];
    } else {
        for (int i = tid; i < KK; i += 256) { nmask[i] = 0.f; cnt[i] = 0; }
        if (tid == 0) fix_cnt[0] = 0;
    }
}

// ---------------- MFMA score kernel: 2-phase double-buffered staging ----------------
// grid (128 token-tiles, 8 code-tiles), 256 thr = 4 waves (2x2 over 128x128 tile)
__global__ __launch_bounds__(256, 2) void k_scores(
    const ushort_t* __restrict__ zh, const ushort_t* __restrict__ zl,
    const ushort_t* __restrict__ ch, const ushort_t* __restrict__ cl,
    const float* __restrict__ cnorm, u64* __restrict__ top2)
{
    __shared__ ushort_t lds[2 * 4 * 128 * 32];    // 2 buffers x (zh,zl,ch,cl tiles) = 2 x 32KB
    const int tid = threadIdx.x;
    const int lane = tid & 63;
    const int wid = tid >> 6;
    const int wm = wid >> 1, wn = wid & 1;
    const int t0 = blockIdx.x * 128;
    const int c0 = blockIdx.y * 128;

    // staging: chunk q = issue*256+tid (16B each); row=q>>2, phys chunk=q&3
    // swizzle: source col8 = pch ^ ((row>>1)&3)  (involution; reads use same XOR)
    const int srow = tid >> 2;
    const int scol = ((tid & 3) ^ ((srow >> 1) & 3)) * 8;
    const size_t zo0 = (size_t)(t0 + srow) * DD + scol;
    const size_t zo1 = zo0 + (size_t)64 * DD;
    const size_t co0 = (size_t)(c0 + srow) * DD + scol;
    const size_t co1 = co0 + (size_t)64 * DD;

    const int l15 = lane & 15, kc = lane >> 4;
    int a_addr[4], b_addr[4];
#pragma unroll
    for (int i = 0; i < 4; ++i) {
        int ar = wm * 64 + i * 16 + l15;
        a_addr[i] = ar * 64 + ((kc ^ ((ar >> 1) & 3)) << 4);
        int br = wn * 64 + i * 16 + l15;
        b_addr[i] = br * 64 + ((kc ^ ((br >> 1) & 3)) << 4);
    }

    f32x4v acc[4][4];
    const f32x4v zf = {0.f, 0.f, 0.f, 0.f};
#pragma unroll
    for (int i = 0; i < 4; ++i)
#pragma unroll
        for (int j = 0; j < 4; ++j) acc[i][j] = zf;

    const char* ldsb = (const char*)lds;
    const int wbase = wid * 64;

    // STAGE(ptr, rowoff, issue_slot, dbyte_off_in_D, buf): lds elem offset = buf*16384 + (issue*256+wbase)*8
#define STAGE(PTR, OFF, ISSUE, D0, BUF)                                               \
    __builtin_amdgcn_global_load_lds(                                                 \
        (const __attribute__((address_space(1))) unsigned int*)((PTR) + (OFF) + (D0)),   \
        (__attribute__((address_space(3))) unsigned int*)(lds + (BUF) * 16384 + (((ISSUE) * 256 + wbase) * 8)), \
        16, 0, 0);
#define STAGE8(D0, BUF)                       \
    STAGE(zh, zo0, 0, D0, BUF) STAGE(zh, zo1, 1, D0, BUF) \
    STAGE(zl, zo0, 2, D0, BUF) STAGE(zl, zo1, 3, D0, BUF) \
    STAGE(ch, co0, 4, D0, BUF) STAGE(ch, co1, 5, D0, BUF) \
    STAGE(cl, co0, 6, D0, BUF) STAGE(cl, co1, 7, D0, BUF)

    // prologue: stage dk=0 into buffer 0, drain, barrier
    STAGE8(0, 0)
    __syncthreads();

    int cur = 0;
    for (int dk = 0; dk < 16; ++dk) {
        // issue next tile's loads into the other buffer FIRST (latency hides under MFMA)
        const int d0n = ((dk + 1) & 15) * 32;
        if (cur) { STAGE8(d0n, 0) } else { STAGE8(d0n, 1) }

        const char* base = ldsb + cur * 32768;
        bf16x8 ah[4], al[4], bh[4], bl[4];
#pragma unroll
        for (int i = 0; i < 4; ++i) {
            ah[i] = *(const bf16x8*)(base + a_addr[i]);
            al[i] = *(const bf16x8*)(base + 8192  + a_addr[i]);
            bh[i] = *(const bf16x8*)(base + 16384 + b_addr[i]);
            bl[i] = *(const bf16x8*)(base + 24576 + b_addr[i]);
        }
#pragma unroll
        for (int i = 0; i < 4; ++i)
#pragma unroll
            for (int j = 0; j < 4; ++j) {
                acc[i][j] = __builtin_amdgcn_mfma_f32_16x16x32_bf16(ah[i], bh[j], acc[i][j], 0, 0, 0);
                acc[i][j] = __builtin_amdgcn_mfma_f32_16x16x32_bf16(ah[i], bl[j], acc[i][j], 0, 0, 0);
                acc[i][j] = __builtin_amdgcn_mfma_f32_16x16x32_bf16(al[i], bh[j], acc[i][j], 0, 0, 0);
            }
        __syncthreads();    // single drain+barrier per K-step (vmcnt(0) for next tile, flip)
        cur ^= 1;
    }
#undef STAGE8
#undef STAGE

    // epilogue: s = 0.5||c||^2 - z.c ; per-row top-2 over this wave's 64 codes
    float cn[4];
#pragma unroll
    for (int j = 0; j < 4; ++j) cn[j] = cnorm[c0 + wn * 64 + j * 16 + l15];

    const int g = lane >> 4;
    const int part = blockIdx.y * 2 + wn;    // 16 partitions of 64 codes
#pragma unroll
    for (int i = 0; i < 4; ++i) {
#pragma unroll
        for (int r = 0; r < 4; ++r) {
            u64 k1 = ~0ULL, k2 = ~0ULL;
#pragma unroll
            for (int j = 0; j < 4; ++j) {
                float s = cn[j] - acc[i][j][r];
                u64 key = ((u64)encf(s) << 32) | (unsigned)(c0 + wn * 64 + j * 16 + l15);
                top2_ins(k1, k2, key);
            }
#pragma unroll
            for (int m = 1; m <= 8; m <<= 1) {
                u64 o1 = __shfl_xor(k1, m, 64);
                u64 o2 = __shfl_xor(k2, m, 64);
                top2_mrg(k1, k2, o1, o2);
            }
            if (l15 == 0) {
                int t = t0 + wm * 64 + i * 16 + g * 4 + r;
                top2[(size_t)(part * 2 + 0) * NTOK + t] = k1;
                top2[(size_t)(part * 2 + 1) * NTOK + t] = k2;
            }
        }
    }
}

// ---------------- merge 16 partition top-2s -> provisional argmin + fix flags ----------------
__global__ void k_merge(const u64* __restrict__ top2, int* __restrict__ idx_ws,
                        float* __restrict__ out_idx, int* __restrict__ fix_list,
                        int* __restrict__ fix_cnt, int* __restrict__ flag,
                        u64* __restrict__ packed2) {
    const int t = blockIdx.x * 256 + threadIdx.x;
    u64 k1 = ~0ULL, k2 = ~0ULL;
#pragma unroll
    for (int q = 0; q < 32; ++q) top2_ins(k1, k2, top2[(size_t)q * NTOK + t]);
    const int idx1 = (int)(k1 & 0xffffffffu);
    idx_ws[t] = idx1;
    out_idx[t] = (float)idx1;
    packed2[t] = ~0ULL;
    float v1 = decf((unsigned)(k1 >> 32));
    float v2 = decf((unsigned)(k2 >> 32));
    int f = (v2 - v1 < EPSM) ? 1 : 0;
    flag[t] = f;
    if (f) {
        int p = atomicAdd(fix_cnt, 1);
        fix_list[p] = t;
    }
}

// ---------------- exact f32 rescore: parallel over (token x 256-code chunk) ----------------
// grid-stride over nfix*4 work items; 16 lanes per code, 4 codes/wave in flight
__global__ void k_fixup(const float* __restrict__ z, const float* __restrict__ cw,
                        const float* __restrict__ cnorm, const int* __restrict__ fix_list,
                        const int* __restrict__ fix_cnt, u64* __restrict__ packed2)
{
    const int nwork = fix_cnt[0] * 4;
    const int tid = threadIdx.x, lane = tid & 63, wid = tid >> 6;
    const int l16 = lane & 15;
    const int sub = lane >> 4;       // 0..3: which of 4 parallel codes
    __shared__ float zrow[DD];
    __shared__ u64 best[4];
    for (int w = blockIdx.x; w < nwork; w += gridDim.x) {
        const int t = fix_list[w >> 2];
        const int cbase = (w & 3) * 256;
        if (tid < 128) {
            float4 v = *reinterpret_cast<const float4*>(z + (size_t)t * DD + tid * 4);
            *reinterpret_cast<float4*>(zrow + tid * 4) = v;
        }
        __syncthreads();
        u64 bk = ~0ULL;
        for (int it = 0; it < 16; ++it) {
            const int c = cbase + wid * 64 + it * 4 + sub;
            const float* cr = cw + (size_t)c * DD;
            float p = 0.f;
#pragma unroll
            for (int u = 0; u < 32; ++u) p = fmaf(zrow[l16 + u * 16], cr[l16 + u * 16], p);
#pragma unroll
            for (int m = 8; m > 0; m >>= 1) p += __shfl_xor(p, m, 16);
            if (l16 == 0) {
                u64 key = ((u64)encf(cnorm[c] - p) << 32) | (unsigned)c;
                if (key < bk) bk = key;
            }
        }
#pragma unroll
        for (int m = 16; m < 64; m <<= 1) {
            u64 o = __shfl_xor(bk, m, 64);
            if (o < bk) bk = o;
        }
        if (lane == 0) best[wid] = bk;
        __syncthreads();
        if (tid == 0) {
            u64 b = best[0];
            if (best[1] < b) b = best[1];
            if (best[2] < b) b = best[2];
            if (best[3] < b) b = best[3];
            atomicMin(&packed2[t], b);
        }
        __syncthreads();
    }
}

// ---------------- gather hidden + loss partials + histogram (final idx) ----------------
__global__ void k_post(const float* __restrict__ z, const float* __restrict__ mask,
                       const float* __restrict__ cw, int* __restrict__ idx_ws,
                       const int* __restrict__ flag, const u64* __restrict__ packed2,
                       float* __restrict__ out_hidden, float* __restrict__ out_idx,
                       float* __restrict__ partials, int* __restrict__ cnt,
                       float* __restrict__ nmask)
{
    const int tid = threadIdx.x, lane = tid & 63, wid = tid >> 6;
    const int t = blockIdx.x * 4 + wid;
    int idx = idx_ws[t];
    if (flag[t]) {
        idx = (int)(packed2[t] & 0xffffffffu);
        if (lane == 0) { idx_ws[t] = idx; out_idx[t] = (float)idx; }
    }
    const float m = mask[t];
    if (lane == 0) {
        atomicAdd(&cnt[idx], 1);
        atomicAdd(&nmask[idx], m);
    }
    const float* zr = z + (size_t)t * DD;
    const float* cr = cw + (size_t)idx * DD;
    float4 z0 = *reinterpret_cast<const float4*>(zr + lane * 4);
    float4 z1 = *reinterpret_cast<const float4*>(zr + 256 + lane * 4);
    float4 q0 = *reinterpret_cast<const float4*>(cr + lane * 4);
    float4 q1 = *reinterpret_cast<const float4*>(cr + 256 + lane * 4);
    float* hr = out_hidden + (size_t)t * DD;
    *reinterpret_cast<float4*>(hr + lane * 4) = q0;
    *reinterpret_cast<float4*>(hr + 256 + lane * 4) = q1;
    float d2 = 0.f;
    float dx;
    dx = z0.x - q0.x; d2 = fmaf(dx, dx, d2);
    dx = z0.y - q0.y; d2 = fmaf(dx, dx, d2);
    dx = z0.z - q0.z; d2 = fmaf(dx, dx, d2);
    dx = z0.w - q0.w; d2 = fmaf(dx, dx, d2);
    dx = z1.x - q1.x; d2 = fmaf(dx, dx, d2);
    dx = z1.y - q1.y; d2 = fmaf(dx, dx, d2);
    dx = z1.z - q1.z; d2 = fmaf(dx, dx, d2);
    dx = z1.w - q1.w; d2 = fmaf(dx, dx, d2);
#pragma unroll
    for (int off = 32; off > 0; off >>= 1) d2 += __shfl_down(d2, off, 64);
    __shared__ float ls[4], ms[4];
    if (lane == 0) { ls[wid] = m * d2 * (1.f / DD); ms[wid] = m; }
    __syncthreads();
    if (tid == 0) {
        partials[blockIdx.x]        = ls[0] + ls[1] + ls[2] + ls[3];
        partials[4096 + blockIdx.x] = ms[0] + ms[1] + ms[2] + ms[3];
    }
}

// ---------------- exclusive scan of counts (1024) ----------------
__global__ void k_scan(const int* __restrict__ cnt, int* __restrict__ offs, int* __restrict__ offs2) {
    __shared__ int s[KK];
    const int t = threadIdx.x;
    const int c = cnt[t];
    s[t] = c;
    __syncthreads();
    for (int d = 1; d < KK; d <<= 1) {
        int v = (t >= d) ? s[t - d] : 0;
        __syncthreads();
        s[t] += v;
        __syncthreads();
    }
    const int ex = s[t] - c;
    offs[t] = ex;
    offs2[t] = ex;
}

// ---------------- scatter tokens sorted by code (+ aligned code array) ----------------
__global__ void k_scatter(const int* __restrict__ idx_ws, int* __restrict__ offs2,
                          int* __restrict__ sorted, int* __restrict__ scode) {
    const int t = blockIdx.x * 256 + threadIdx.x;
    const int k = idx_ws[t];
    const int p = atomicAdd(&offs2[k], 1);
    sorted[p] = t;
    scode[p] = k;
}

// ---------------- token-parallel segmented dw: 1024 blocks x 16 sorted tokens ----------------
__global__ void k_dw(const float* __restrict__ z, const float* __restrict__ mask,
                     const int* __restrict__ sorted, const int* __restrict__ scode,
                     float* __restrict__ dwacc)
{
    const int tid = threadIdx.x;
    const int o = blockIdx.x * 16;
    __shared__ int stok[16], scod[16];
    if (tid < 16) { stok[tid] = sorted[o + tid]; scod[tid] = scode[o + tid]; }
    __syncthreads();
    // prefetch all 16 row-slices (independent loads; single drain)
    float2 zv[16];
    float  mv[16];
#pragma unroll
    for (int m = 0; m < 16; ++m) {
        const int t = stok[m];
        mv[m] = mask[t];
        zv[m] = *reinterpret_cast<const float2*>(z + (size_t)t * DD + tid * 2);
    }
    float a0 = 0.f, a1 = 0.f;
    int kcur = scod[0];
#pragma unroll
    for (int m = 0; m < 16; ++m) {
        const int k = scod[m];
        if (k != kcur) {           // wave-uniform branch (code boundary)
            atomicAdd(&dwacc[(size_t)kcur * DD + tid * 2],     a0);
            atomicAdd(&dwacc[(size_t)kcur * DD + tid * 2 + 1], a1);
            a0 = 0.f; a1 = 0.f; kcur = k;
        }
        a0 = fmaf(mv[m], zv[m].x, a0);
        a1 = fmaf(mv[m], zv[m].y, a1);
    }
    atomicAdd(&dwacc[(size_t)kcur * DD + tid * 2],     a0);
    atomicAdd(&dwacc[(size_t)kcur * DD + tid * 2 + 1], a1);
}

// ---------------- fused tail: new_weight EMA + loss/new_count scalars ----------------
// 512 blocks: all do a 1024-float nw chunk; block 0 additionally does scalars
__global__ void k_tail(const float* __restrict__ ema_w, const float* __restrict__ dwacc,
                       const float* __restrict__ ema_count, const float* __restrict__ nmask,
                       const float* __restrict__ partials, float* __restrict__ out_nw,
                       float* __restrict__ out_count, float* __restrict__ out_loss)
{
    const int tid = threadIdx.x;
    const size_t i = ((size_t)blockIdx.x * 256 + tid) * 4;
    float4 e = *reinterpret_cast<const float4*>(ema_w + i);
    float4 d = *reinterpret_cast<const float4*>(dwacc + i);
    float4 r;
    r.x = DECAYF * e.x + OMDEC * d.x;
    r.y = DECAYF * e.y + OMDEC * d.y;
    r.z = DECAYF * e.z + OMDEC * d.z;
    r.w = DECAYF * e.w + OMDEC * d.w;
    *reinterpret_cast<float4*>(out_nw + i) = r;

    if (blockIdx.x == 0) {
        __shared__ float rl[256], rm[256], re[256];
        float ls = 0.f, ms = 0.f, es = 0.f;
        for (int j = tid; j < 4096; j += 256) { ls += partials[j]; ms += partials[4096 + j]; }
        for (int j = tid; j < KK; j += 256) es += ema_count[j];
        rl[tid] = ls; rm[tid] = ms; re[tid] = es;
        __syncthreads();
        for (int s = 128; s > 0; s >>= 1) {
            if (tid < s) { rl[tid] += rl[tid + s]; rm[tid] += rm[tid + s]; re[tid] += re[tid + s]; }
            __syncthreads();
        }
        const float masksum = rm[0];
        const float total = DECAYF * re[0] + OMDEC * masksum;
        const float scale = total / (total + KK * EPSF);
        for (int j = tid; j < KK; j += 256) {
            float raw = DECAYF * ema_count[j] + OMDEC * nmask[j];
            out_count[j] = (raw + EPSF) * scale;
        }
        if (tid == 0) out_loss[0] = 2.5f * rl[0] / masksum;   // LOSS_SCALE*COMMIT_COEF = 2.5
    }
}

extern "C" void kernel_launch(void* const* d_in, const int* in_sizes, int n_in,
                              void* d_out, int out_size, void* d_ws, size_t ws_size,
                              hipStream_t stream)
{
    const float* z         = (const float*)d_in[0];
    const float* mask      = (const float*)d_in[1];
    const float* cw        = (const float*)d_in[2];
    const float* ema_count = (const float*)d_in[3];
    const float* ema_w     = (const float*)d_in[4];

    float* out        = (float*)d_out;
    float* out_hidden = out;                               // [N, D]
    float* out_idx    = out + (size_t)NTOK * DD;           // [N]
    float* out_loss   = out_idx + NTOK;                    // [1]
    float* out_count  = out_loss + 1;                      // [K]
    float* out_nw     = out_count + KK;                    // [K, D]

    // workspace layout (~43 MB)
    ushort_t* zh   = (ushort_t*)d_ws;                      // 16 MB
    ushort_t* zl   = zh + (size_t)NTOK * DD;               // 16 MB
    ushort_t* ch   = zl + (size_t)NTOK * DD;               // 1 MB
    ushort_t* cl   = ch + (size_t)KK * DD;                 // 1 MB
    float* cnorm   = (float*)(cl + (size_t)KK * DD);       // 4 KB
    u64* top2      = (u64*)(cnorm + KK);                   // 32*N u64 = 4 MB
    u64* packed2   = top2 + (size_t)32 * NTOK;             // N u64 = 128 KB
    float* partials = (float*)(packed2 + NTOK);            // 8192 f32
    float* nmask   = partials + 8192;                      // 1024
    int* cnt       = (int*)(nmask + KK);                   // 1024
    int* offs      = cnt + KK;                             // 1024
    int* offs2     = offs + KK;                            // 1024
    int* sorted    = offs2 + KK;                           // N
    int* scode     = sorted + NTOK;                        // N
    int* fix_list  = scode + NTOK;                         // N
    int* fix_cnt   = fix_list + NTOK;                      // 1 (+pad)
    int* flag      = fix_cnt + 16;                         // N
    int* idx_ws    = flag + NTOK;                          // N
    float* dwacc   = (float*)(idx_ws + NTOK);              // K*D f32 = 2 MB

    k_prep   <<<dim3(5121),     dim3(256),  0, stream>>>(z, cw, zh, zl, ch, cl, cnorm,
                                                         nmask, cnt, fix_cnt, dwacc);
    k_scores <<<dim3(128, 8),   dim3(256),  0, stream>>>(zh, zl, ch, cl, cnorm, top2);
    k_merge  <<<dim3(64),       dim3(256),  0, stream>>>(top2, idx_ws, out_idx, fix_list,
                                                         fix_cnt, flag, packed2);
    k_fixup  <<<dim3(2048),     dim3(256),  0, stream>>>(z, cw, cnorm, fix_list, fix_cnt, packed2);
    k_post   <<<dim3(4096),     dim3(256),  0, stream>>>(z, mask, cw, idx_ws, flag, packed2,
                                                         out_hidden, out_idx, partials, cnt, nmask);
    k_scan   <<<dim3(1),        dim3(1024), 0, stream>>>(cnt, offs, offs2);
    k_scatter<<<dim3(64),       dim3(256),  0, stream>>>(idx_ws, offs2, sorted, scode);
    k_dw     <<<dim3(1024),     dim3(256),  0, stream>>>(z, mask, sorted, scode, dwacc);
    k_tail   <<<dim3(512),      dim3(256),  0, stream>>>(ema_w, dwacc, ema_count, nmask,
                                                         partials, out_nw, out_count, out_loss);
}